// Round 10
// baseline (178.166 us; speedup 1.0000x reference)
//
#include <hip/hip_runtime.h>
#include <cstdint>

typedef __bf16 bf16;
typedef __bf16 bf16x4 __attribute__((ext_vector_type(4)));
typedef __bf16 bf16x8 __attribute__((ext_vector_type(8)));
typedef float floatx4 __attribute__((ext_vector_type(4)));

typedef const __attribute__((address_space(1))) void* as1_cvptr;
typedef __attribute__((address_space(3))) void* as3_vptr;

__device__ __forceinline__ void gl_lds16(const void* g, void* l) {
  __builtin_amdgcn_global_load_lds((as1_cvptr)(uintptr_t)g,
                                   (as3_vptr)(uint32_t)(uintptr_t)l, 16, 0, 0);
}

#define EMBED 1024
#define SEQ 2048
#define NH 16
#define DH 64
// softmax scale folded into Q at projection time: 0.125 * log2(e)
#define QSCALE 0.18033688f

// ---------------------------------------------------------------------------
// Kernel A: prep — grid (256,4). z<3: transpose+downcast W z; z=3: x->bf16.
// ---------------------------------------------------------------------------
__global__ __launch_bounds__(256) void prep(
    const float* __restrict__ x, const float* __restrict__ Wq,
    const float* __restrict__ Wk, const float* __restrict__ Wv,
    bf16* __restrict__ xb, bf16* __restrict__ Wqt,
    bf16* __restrict__ Wkt, bf16* __restrict__ Wvt) {
  __shared__ __align__(16) bf16 tile[64][72];
  int z = blockIdx.y;
  int t = threadIdx.x;
  if (z == 3) {
    size_t base = ((size_t)blockIdx.x * 256 + t) * 8;
#pragma unroll
    for (int it = 0; it < 8; ++it) {
      size_t i = base + (size_t)it * (256 * 256 * 8);
      floatx4 a = *(const floatx4*)(x + i);
      floatx4 bv = *(const floatx4*)(x + i + 4);
      bf16x8 o;
#pragma unroll
      for (int j = 0; j < 4; ++j) { o[j] = (bf16)a[j]; o[4 + j] = (bf16)bv[j]; }
      *(bf16x8*)(xb + i) = o;
    }
    return;
  }
  const float* W = (z == 0) ? Wq : (z == 1) ? Wk : Wv;
  bf16* Wt = (z == 0) ? Wqt : (z == 1) ? Wkt : Wvt;
  int k0 = (blockIdx.x >> 4) * 64, n0 = (blockIdx.x & 15) * 64;
  int r = t >> 3, c = (t & 7) * 8;
#pragma unroll
  for (int half = 0; half < 2; ++half) {
    const float* src = &W[(size_t)(k0 + r + half * 32) * EMBED + n0 + c];
    floatx4 f0 = *(const floatx4*)src;
    floatx4 f1 = *(const floatx4*)(src + 4);
    bf16x8 o;
#pragma unroll
    for (int j = 0; j < 4; ++j) { o[j] = (bf16)f0[j]; o[4 + j] = (bf16)f1[j]; }
    *(bf16x8*)&tile[r + half * 32][c] = o;
  }
  __syncthreads();
#pragma unroll
  for (int p = 0; p < 2; ++p) {
    int nn = (t >> 3) + p * 32, kk = (t & 7) * 8;
    bf16x8 v;
#pragma unroll
    for (int i = 0; i < 8; ++i) v[i] = tile[kk + i][nn];
    *(bf16x8*)&Wt[(size_t)(n0 + nn) * EMBED + k0 + kk] = v;
  }
}

// ---------------------------------------------------------------------------
// Kernel B v5: fused QKV — 128x64 tiles for 2x TLP. Grid 1536 (z fastest,
// no XCD swizzle — r9 measured it a regression). 6 blocks/CU x 4 waves =
// 24 waves/CU (vs 12 at 128x128): doubles the latency-hiding TLP that the
// 2-phase barrier-drain structure needs. LDS 24KB dbuf; 2-phase prefetch
// (stage t+1 before compute t, one barrier/step, proven r7).
// Per wave: 64x32 out, acc[4][2], 8 MFMA/step. Packed bf16x4 stores.
// ---------------------------------------------------------------------------
__global__ __launch_bounds__(256) void qkv3(
    const bf16* __restrict__ Xb, const bf16* __restrict__ Wqt,
    const bf16* __restrict__ Wkt, const bf16* __restrict__ Wvt,
    bf16* __restrict__ qo, bf16* __restrict__ ko, bf16* __restrict__ vto) {
  __shared__ __align__(16) bf16 As[2][128 * 32];
  __shared__ __align__(16) bf16 Bs[2][64 * 32];

  int gid = blockIdx.x;
  int z = gid % 3;
  int rem = gid / 3;  // [0,512)

  const bf16* Wt = (z == 0) ? Wqt : (z == 1) ? Wkt : Wvt;
  bf16* out = (z == 0) ? qo : (z == 1) ? ko : vto;
  // z<2: A=Wt m=outdim (8 tiles of 128), B=X n=seq (64 tiles of 64)
  // z=2: A=X  m=seq   (32 tiles of 128), B=Wt n=outdim (16 tiles of 64)
  int m0, n0;
  if (z != 2) { m0 = (rem & 7) * 128; n0 = (rem >> 3) * 64; }
  else        { m0 = (rem & 31) * 128; n0 = (rem >> 5) * 64; }
  const bf16* Asrc = (z == 2) ? Xb : Wt;
  const bf16* Bsrc = (z == 2) ? Wt : Xb;
  float oscale = (z == 0) ? QSCALE : 1.0f;

  int t = threadIdx.x;
  int w = t >> 6, lane = t & 63, ln = lane & 15, quad = lane >> 4;
  int wm = (w >> 1) * 64, wn = (w & 1) * 32;

  floatx4 acc[4][2];
#pragma unroll
  for (int i = 0; i < 4; ++i)
#pragma unroll
    for (int j = 0; j < 2; ++j) acc[i][j] = floatx4{0.f, 0.f, 0.f, 0.f};

  // staging: A 128x32 (2 gl_lds/thread), B 64x32 (1 gl_lds/thread)
  int sr = t >> 2, sc = (t & 3) * 8;
  const bf16* ag = Asrc + (size_t)(m0 + sr) * EMBED + sc;
  const bf16* bg = Bsrc + (size_t)(n0 + sr) * EMBED + sc;  // sr<64 rows used
  int so = sr * 32 + sc;
  bool bstage = (sr < 64);

  // prologue: stage k-step 0 into buffer 0
  gl_lds16(ag, &As[0][so]);
  gl_lds16(ag + (size_t)64 * EMBED, &As[0][so + 64 * 32]);
  if (bstage) gl_lds16(bg, &Bs[0][so]);
  __syncthreads();

  for (int ks = 0; ks < 32; ++ks) {
    int cur = ks & 1, nxt = cur ^ 1;
    if (ks + 1 < 32) {  // prefetch next K-step before compute
      int k0 = (ks + 1) * 32;
      gl_lds16(ag + k0, &As[nxt][so]);
      gl_lds16(ag + k0 + (size_t)64 * EMBED, &As[nxt][so + 64 * 32]);
      if (bstage) gl_lds16(bg + k0, &Bs[nxt][so]);
    }
    const bf16* Ac = As[cur];
    const bf16* Bc = Bs[cur];
    bf16x8 afr[4], bfr[2];
#pragma unroll
    for (int i = 0; i < 4; ++i)
      afr[i] = *(const bf16x8*)&Ac[(wm + i * 16 + ln) * 32 + quad * 8];
#pragma unroll
    for (int j = 0; j < 2; ++j)
      bfr[j] = *(const bf16x8*)&Bc[(wn + j * 16 + ln) * 32 + quad * 8];
#pragma unroll
    for (int i = 0; i < 4; ++i)
#pragma unroll
      for (int j = 0; j < 2; ++j)
        acc[i][j] =
            __builtin_amdgcn_mfma_f32_16x16x32_bf16(afr[i], bfr[j], acc[i][j], 0, 0, 0);
    __syncthreads();  // drains stage loads (vm) + all waves' reads (lgkm)
  }

  // Epilogue: C/D 16x16 layout col=lane&15, row=quad*4+r (rows consecutive)
  if (z != 2) {
#pragma unroll
    for (int i = 0; i < 4; ++i) {
      int od = m0 + wm + i * 16 + quad * 4;  // outdim, aligned 4
      int hq = od >> 6, d0 = od & 63;
#pragma unroll
      for (int j = 0; j < 2; ++j) {
        int c = n0 + wn + j * 16 + ln;  // global seq 0..4095
        int bb = c >> 11, ns = c & 2047;
        bf16x4 pv;
#pragma unroll
        for (int r = 0; r < 4; ++r) pv[r] = (bf16)(acc[i][j][r] * oscale);
        *(bf16x4*)&out[(((size_t)(bb * NH + hq)) * SEQ + ns) * DH + d0] = pv;
      }
    }
  } else {
#pragma unroll
    for (int i = 0; i < 4; ++i) {
      int sq = m0 + wm + i * 16 + quad * 4;  // seq, aligned 4
      int bb = sq >> 11, ns0 = sq & 2047;
#pragma unroll
      for (int j = 0; j < 2; ++j) {
        int od = n0 + wn + j * 16 + ln;
        int hq = od >> 6, d = od & 63;
        bf16x4 pv;
#pragma unroll
        for (int r = 0; r < 4; ++r) pv[r] = (bf16)acc[i][j][r];
        *(bf16x4*)&out[(((size_t)(bb * NH + hq)) * DH + d) * SEQ + ns0] = pv;
      }
    }
  }
}

// ---------------------------------------------------------------------------
// Kernel C: flash v11 (unchanged — 61.7us, FETCH 13.3MB). v10 core + XCD
// swizzle v=(hw&7)*64+(hw>>3): each XCD owns 4 heads x 16 q-tiles, K/V
// L2-resident.
// ---------------------------------------------------------------------------
__global__ __launch_bounds__(1024, 8) void flash(
    const bf16* __restrict__ Qg, const bf16* __restrict__ Kg,
    const bf16* __restrict__ Vtg, float* __restrict__ Og) {
  __shared__ __align__(16) char smem[73728];
  bf16* Ks = (bf16*)smem;                  // [2][64][72]
  bf16* Vs = (bf16*)(smem + 18432);        // [2][64][72]  (V^T: [d][key])
  bf16* Ps = (bf16*)(smem + 36864);        // [16 waves][16][72]
  float* Om = (float*)smem;                // merge overlay: [128 q][68]
  float* Lm = (float*)(smem + 34816);      // merge overlay: [128] (half1's l)

  int t = threadIdx.x, w = t >> 6, lane = t & 63, ln = lane & 15, quad = lane >> 4;
  int qg = w >> 1, half = w & 1;
  int hwid = blockIdx.y * 16 + blockIdx.x;
  int v = (hwid & 7) * 64 + (hwid >> 3);   // XCD-contiguous virtual id
  int qt = v & 15, bh = v >> 4;
  int b = bh >> 4, h = bh & 15;
  const bf16* Q = Qg + (size_t)bh * SEQ * DH;
  const bf16* K = Kg + (size_t)bh * SEQ * DH;
  const bf16* Vt = Vtg + (size_t)bh * DH * SEQ;
  int q0 = qt * 128 + qg * 16;

  // Q as B-operand: B[n=q(ln)][k=d(quad*8+j)] — Q already carries QSCALE
  bf16x8 bq[2];
#pragma unroll
  for (int kc = 0; kc < 2; ++kc)
    bq[kc] = *(const bf16x8*)&Q[(size_t)(q0 + ln) * DH + kc * 32 + quad * 8];

  // constant-ones B fragment for the l-accumulating MFMA
  bf16x8 ones;
#pragma unroll
  for (int j = 0; j < 8; ++j) ones[j] = (bf16)1.0f;

  floatx4 oacc[4];
  floatx4 oL = floatx4{0.f, 0.f, 0.f, 0.f};
#pragma unroll
  for (int dt = 0; dt < 4; ++dt) oacc[dt] = floatx4{0.f, 0.f, 0.f, 0.f};

  // staging roles: threads [0,512) stage half 0's tiles, [512,1024) half 1's.
  // Within a half: j<256 -> K (32B/thread), j>=256 -> V (32B/thread).
  int sh = t >> 9, st = t & 511;
  int ar = st >> 8, j = st & 255;
  int kr = j >> 2, kcol = (j & 3) * 16;  // row 0..63, 32B col chunk
  const bf16* gsrc;
  bf16* ldst;
  int gstep;
  if (ar == 0) {
    gsrc = K + (size_t)(sh * 1024 + kr) * DH + kcol;   // K row kr, d-chunk
    ldst = Ks + sh * 4608 + kr * 72 + kcol;
    gstep = 64 * DH;                                   // 64 keys per tile
  } else {
    gsrc = Vt + (size_t)kr * SEQ + sh * 1024 + kcol;   // V^T d=kr, key-chunk
    ldst = Vs + sh * 4608 + kr * 72 + kcol;
    gstep = 64;                                        // 64 keys per tile
  }

  bf16x8 p0 = *(const bf16x8*)gsrc;
  bf16x8 p1 = *(const bf16x8*)(gsrc + 8);

  const bf16* Ksh = Ks + half * 4608;
  const bf16* Vsh = Vs + half * 4608;
  bf16* Pw = Ps + w * (16 * 72);

  for (int it = 0; it < 16; ++it) {
    __syncthreads();
    *(bf16x8*)ldst = p0;
    *(bf16x8*)(ldst + 8) = p1;
    __syncthreads();

    if (it + 1 < 16) {
      const bf16* gnext = gsrc + (size_t)(it + 1) * gstep;
      p0 = *(const bf16x8*)gnext;
      p1 = *(const bf16x8*)(gnext + 8);
    }

    // S^T = K.Q^T: D[m=key][n=q]; s[nt][r] = score(q=ln, key=nt*16+quad*4+r)
    floatx4 s[4];
#pragma unroll
    for (int nt = 0; nt < 4; ++nt) s[nt] = floatx4{0.f, 0.f, 0.f, 0.f};
#pragma unroll
    for (int kc = 0; kc < 2; ++kc) {
#pragma unroll
      for (int nt = 0; nt < 4; ++nt) {
        bf16x8 ak = *(const bf16x8*)&Ksh[(nt * 16 + ln) * 72 + kc * 32 + quad * 8];
        s[nt] = __builtin_amdgcn_mfma_f32_16x16x32_bf16(ak, bq[kc], s[nt], 0, 0, 0);
      }
    }

    // p = exp2(s), raw v_exp_f32; packed b64 P writes; NO scalar li adds
#pragma unroll
    for (int nt = 0; nt < 4; ++nt) {
      float p0f = __builtin_amdgcn_exp2f(s[nt][0]);
      float p1f = __builtin_amdgcn_exp2f(s[nt][1]);
      float p2f = __builtin_amdgcn_exp2f(s[nt][2]);
      float p3f = __builtin_amdgcn_exp2f(s[nt][3]);
      bf16x4 pq = {(bf16)p0f, (bf16)p1f, (bf16)p2f, (bf16)p3f};
      *(bf16x4*)&Pw[ln * 72 + nt * 16 + quad * 4] = pq;
    }

    // O += P.V: A = P[q][key] (m=q), B = V^T[d][key] (n=d); same-wave LDS order
    // l += P.1: same A, B = ones (const reg) -> lane's oL[r] = l(quad*4+r)
#pragma unroll
    for (int kc2 = 0; kc2 < 2; ++kc2) {
      bf16x8 ap = *(const bf16x8*)&Pw[ln * 72 + kc2 * 32 + quad * 8];
      oL = __builtin_amdgcn_mfma_f32_16x16x32_bf16(ap, ones, oL, 0, 0, 0);
#pragma unroll
      for (int dt = 0; dt < 4; ++dt) {
        bf16x8 bv = *(const bf16x8*)&Vsh[(dt * 16 + ln) * 72 + kc2 * 32 + quad * 8];
        oacc[dt] = __builtin_amdgcn_mfma_f32_16x16x32_bf16(ap, bv, oacc[dt], 0, 0, 0);
      }
    }
  }

  // ---- split-K merge: O = O_half0 + O_half1, l = l0 + l1 (exact) ----
  __syncthreads();  // all compute (and last-tile LDS reads) done; reuse smem
  if (half) {
    if (ln == 0) {
#pragma unroll
      for (int r = 0; r < 4; ++r) Lm[qg * 16 + quad * 4 + r] = oL[r];
    }
#pragma unroll
    for (int r = 0; r < 4; ++r) {
      int q = qg * 16 + quad * 4 + r;
#pragma unroll
      for (int dt = 0; dt < 4; ++dt) Om[q * 68 + dt * 16 + ln] = oacc[dt][r];
    }
  }
  __syncthreads();
  if (!half) {
#pragma unroll
    for (int r = 0; r < 4; ++r) {
      int qq = qg * 16 + quad * 4 + r;
      float lt = oL[r] + Lm[qq];   // own half's l (all ln identical) + other
      float inv = 1.0f / lt;
      int ns = qt * 128 + qq;
#pragma unroll
      for (int dt = 0; dt < 4; ++dt) {
        int d = dt * 16 + ln;
        float val = (oacc[dt][r] + Om[qq * 68 + d]) * inv;
        Og[((size_t)(b * SEQ + ns)) * EMBED + h * DH + d] = val;
      }
    }
  }
}

// ---------------------------------------------------------------------------
// ws (38 MB): q [0,4M) k [4M,8M) vt [8M,12M) wqt..wvt [12M,15M) xb [15M,19M)
// ---------------------------------------------------------------------------
extern "C" void kernel_launch(void* const* d_in, const int* in_sizes, int n_in,
                              void* d_out, int out_size, void* d_ws, size_t ws_size,
                              hipStream_t stream) {
  const int XEL = 2 * 2048 * 1024;
  const float *x, *Wq, *Wk, *Wv;
  if (in_sizes[0] == XEL) {
    x = (const float*)d_in[0];
    Wq = (const float*)d_in[1];
    Wk = (const float*)d_in[2];
    Wv = (const float*)d_in[3];
  } else {
    Wk = (const float*)d_in[0];
    Wq = (const float*)d_in[1];
    Wv = (const float*)d_in[2];
    x = (const float*)d_in[3];
  }
  bf16* ws = (bf16*)d_ws;

  const size_t M1 = 1024 * 1024;
  bf16* q_ws = ws;
  bf16* k_ws = ws + 4 * M1;
  bf16* vt_ws = ws + 8 * M1;
  bf16* wqt = ws + 12 * M1;
  bf16* wkt = ws + 13 * M1;
  bf16* wvt = ws + 14 * M1;
  bf16* xb = ws + 15 * M1;

  prep<<<dim3(256, 4), 256, 0, stream>>>(x, Wq, Wk, Wv, xb, wqt, wkt, wvt);
  qkv3<<<dim3(1536), 256, 0, stream>>>(xb, wqt, wkt, wvt, q_ws, k_ws, vt_ws);
  flash<<<dim3(16, 32), 1024, 0, stream>>>(q_ws, k_ws, vt_ws, (float*)d_out);
}

// Round 11
// 167.221 us; speedup vs baseline: 1.0655x; 1.0655x over previous
//
#include <hip/hip_runtime.h>
#include <cstdint>

typedef __bf16 bf16;
typedef __bf16 bf16x4 __attribute__((ext_vector_type(4)));
typedef __bf16 bf16x8 __attribute__((ext_vector_type(8)));
typedef float floatx4 __attribute__((ext_vector_type(4)));

typedef const __attribute__((address_space(1))) void* as1_cvptr;
typedef __attribute__((address_space(3))) void* as3_vptr;

__device__ __forceinline__ void gl_lds16(const void* g, void* l) {
  __builtin_amdgcn_global_load_lds((as1_cvptr)(uintptr_t)g,
                                   (as3_vptr)(uint32_t)(uintptr_t)l, 16, 0, 0);
}

#define EMBED 1024
#define SEQ 2048
#define NH 16
#define DH 64
// softmax scale folded into Q at projection time: 0.125 * log2(e)
#define QSCALE 0.18033688f

// ---------------------------------------------------------------------------
// Kernel A: prep — grid (256,4). z<3: transpose+downcast W z; z=3: x->bf16.
// ---------------------------------------------------------------------------
__global__ __launch_bounds__(256) void prep(
    const float* __restrict__ x, const float* __restrict__ Wq,
    const float* __restrict__ Wk, const float* __restrict__ Wv,
    bf16* __restrict__ xb, bf16* __restrict__ Wqt,
    bf16* __restrict__ Wkt, bf16* __restrict__ Wvt) {
  __shared__ __align__(16) bf16 tile[64][72];
  int z = blockIdx.y;
  int t = threadIdx.x;
  if (z == 3) {
    size_t base = ((size_t)blockIdx.x * 256 + t) * 8;
#pragma unroll
    for (int it = 0; it < 8; ++it) {
      size_t i = base + (size_t)it * (256 * 256 * 8);
      floatx4 a = *(const floatx4*)(x + i);
      floatx4 bv = *(const floatx4*)(x + i + 4);
      bf16x8 o;
#pragma unroll
      for (int j = 0; j < 4; ++j) { o[j] = (bf16)a[j]; o[4 + j] = (bf16)bv[j]; }
      *(bf16x8*)(xb + i) = o;
    }
    return;
  }
  const float* W = (z == 0) ? Wq : (z == 1) ? Wk : Wv;
  bf16* Wt = (z == 0) ? Wqt : (z == 1) ? Wkt : Wvt;
  int k0 = (blockIdx.x >> 4) * 64, n0 = (blockIdx.x & 15) * 64;
  int r = t >> 3, c = (t & 7) * 8;
#pragma unroll
  for (int half = 0; half < 2; ++half) {
    const float* src = &W[(size_t)(k0 + r + half * 32) * EMBED + n0 + c];
    floatx4 f0 = *(const floatx4*)src;
    floatx4 f1 = *(const floatx4*)(src + 4);
    bf16x8 o;
#pragma unroll
    for (int j = 0; j < 4; ++j) { o[j] = (bf16)f0[j]; o[4 + j] = (bf16)f1[j]; }
    *(bf16x8*)&tile[r + half * 32][c] = o;
  }
  __syncthreads();
#pragma unroll
  for (int p = 0; p < 2; ++p) {
    int nn = (t >> 3) + p * 32, kk = (t & 7) * 8;
    bf16x8 v;
#pragma unroll
    for (int i = 0; i < 8; ++i) v[i] = tile[kk + i][nn];
    *(bf16x8*)&Wt[(size_t)(n0 + nn) * EMBED + k0 + kk] = v;
  }
}

// ---------------------------------------------------------------------------
// Kernel B v3 (measured best, r7/r8): fused QKV — 128x128 tiles, 768 blocks,
// NO XCD swizzle (r9 measured swizzle -3.4us), 2-phase double-buffered
// prefetch (stage t+1 before compute t, one barrier/step). Packed bf16x4
// stores (C rows = fastest dim).
// ---------------------------------------------------------------------------
__global__ __launch_bounds__(256) void qkv3(
    const bf16* __restrict__ Xb, const bf16* __restrict__ Wqt,
    const bf16* __restrict__ Wkt, const bf16* __restrict__ Wvt,
    bf16* __restrict__ qo, bf16* __restrict__ ko, bf16* __restrict__ vto) {
  __shared__ __align__(16) bf16 As[2][128 * 32];
  __shared__ __align__(16) bf16 Bs[2][128 * 32];

  int gid = blockIdx.x;
  int z = gid % 3;
  int rem = gid / 3;
  int bxx = rem & 7, byy = rem >> 3;  // bxx: outdim tile (8), byy: seq tile (32)

  const bf16* Wt = (z == 0) ? Wqt : (z == 1) ? Wkt : Wvt;
  bf16* out = (z == 0) ? qo : (z == 1) ? ko : vto;
  int m0 = (z == 2 ? byy : bxx) * 128;
  int n0 = (z == 2 ? bxx : byy) * 128;
  const bf16* Asrc = (z == 2) ? Xb : Wt;
  const bf16* Bsrc = (z == 2) ? Wt : Xb;
  float oscale = (z == 0) ? QSCALE : 1.0f;

  int t = threadIdx.x;
  int w = t >> 6, lane = t & 63, ln = lane & 15, quad = lane >> 4;
  int wm = (w >> 1) * 64, wn = (w & 1) * 64;

  floatx4 acc[4][4];
#pragma unroll
  for (int i = 0; i < 4; ++i)
#pragma unroll
    for (int j = 0; j < 4; ++j) acc[i][j] = floatx4{0.f, 0.f, 0.f, 0.f};

  int sr = t >> 2, sc = (t & 3) * 8;
  const bf16* ag = Asrc + (size_t)(m0 + sr) * EMBED + sc;
  const bf16* bg = Bsrc + (size_t)(n0 + sr) * EMBED + sc;
  int so = sr * 32 + sc;

  // prologue: stage k-step 0 into buffer 0
  gl_lds16(ag, &As[0][so]);
  gl_lds16(ag + (size_t)64 * EMBED, &As[0][so + 64 * 32]);
  gl_lds16(bg, &Bs[0][so]);
  gl_lds16(bg + (size_t)64 * EMBED, &Bs[0][so + 64 * 32]);
  __syncthreads();

  for (int ks = 0; ks < 32; ++ks) {
    int cur = ks & 1, nxt = cur ^ 1;
    if (ks + 1 < 32) {  // issue next tile's loads BEFORE compute (prefetch)
      int k0 = (ks + 1) * 32;
      gl_lds16(ag + k0, &As[nxt][so]);
      gl_lds16(ag + k0 + (size_t)64 * EMBED, &As[nxt][so + 64 * 32]);
      gl_lds16(bg + k0, &Bs[nxt][so]);
      gl_lds16(bg + k0 + (size_t)64 * EMBED, &Bs[nxt][so + 64 * 32]);
    }
    const bf16* Ac = As[cur];
    const bf16* Bc = Bs[cur];
    bf16x8 afr[4], bfr[4];
#pragma unroll
    for (int i = 0; i < 4; ++i)
      afr[i] = *(const bf16x8*)&Ac[(wm + i * 16 + ln) * 32 + quad * 8];
#pragma unroll
    for (int j = 0; j < 4; ++j)
      bfr[j] = *(const bf16x8*)&Bc[(wn + j * 16 + ln) * 32 + quad * 8];
#pragma unroll
    for (int i = 0; i < 4; ++i)
#pragma unroll
      for (int j = 0; j < 4; ++j)
        acc[i][j] =
            __builtin_amdgcn_mfma_f32_16x16x32_bf16(afr[i], bfr[j], acc[i][j], 0, 0, 0);
    __syncthreads();  // drains my stage loads (vm) + all waves' reads (lgkm)
  }

  // Epilogue: C/D 16x16 layout col=lane&15, row=quad*4+r (rows consecutive)
  if (z != 2) {
#pragma unroll
    for (int i = 0; i < 4; ++i) {
      int od = m0 + wm + i * 16 + quad * 4;  // aligned 4, no h-crossing
      int hq = od >> 6, d0 = od & 63;
#pragma unroll
      for (int j = 0; j < 4; ++j) {
        int c = n0 + wn + j * 16 + ln;  // global seq 0..4095
        int bb = c >> 11, ns = c & 2047;
        bf16x4 pv;
#pragma unroll
        for (int r = 0; r < 4; ++r) pv[r] = (bf16)(acc[i][j][r] * oscale);
        *(bf16x4*)&out[(((size_t)(bb * NH + hq)) * SEQ + ns) * DH + d0] = pv;
      }
    }
  } else {
#pragma unroll
    for (int i = 0; i < 4; ++i) {
      int sq = m0 + wm + i * 16 + quad * 4;  // aligned 4, no b-crossing
      int bb = sq >> 11, ns0 = sq & 2047;
#pragma unroll
      for (int j = 0; j < 4; ++j) {
        int od = n0 + wn + j * 16 + ln;
        int hq = od >> 6, d = od & 63;
        bf16x4 pv;
#pragma unroll
        for (int r = 0; r < 4; ++r) pv[r] = (bf16)acc[i][j][r];
        *(bf16x4*)&out[(((size_t)(bb * NH + hq)) * DH + d) * SEQ + ns0] = pv;
      }
    }
  }
}

// ---------------------------------------------------------------------------
// Kernel C: flash v11 (measured best, r9/r10 — 61.7-62.4us, FETCH 13.3MB).
// v10 core (raw v_exp_f32, l-via-MFMA-ones) + XCD swizzle
// v=(hw&7)*64+(hw>>3): each XCD owns 4 heads x 16 q-tiles, K/V L2-resident.
// ---------------------------------------------------------------------------
__global__ __launch_bounds__(1024, 8) void flash(
    const bf16* __restrict__ Qg, const bf16* __restrict__ Kg,
    const bf16* __restrict__ Vtg, float* __restrict__ Og) {
  __shared__ __align__(16) char smem[73728];
  bf16* Ks = (bf16*)smem;                  // [2][64][72]
  bf16* Vs = (bf16*)(smem + 18432);        // [2][64][72]  (V^T: [d][key])
  bf16* Ps = (bf16*)(smem + 36864);        // [16 waves][16][72]
  float* Om = (float*)smem;                // merge overlay: [128 q][68]
  float* Lm = (float*)(smem + 34816);      // merge overlay: [128] (half1's l)

  int t = threadIdx.x, w = t >> 6, lane = t & 63, ln = lane & 15, quad = lane >> 4;
  int qg = w >> 1, half = w & 1;
  int hwid = blockIdx.y * 16 + blockIdx.x;
  int v = (hwid & 7) * 64 + (hwid >> 3);   // XCD-contiguous virtual id
  int qt = v & 15, bh = v >> 4;
  int b = bh >> 4, h = bh & 15;
  const bf16* Q = Qg + (size_t)bh * SEQ * DH;
  const bf16* K = Kg + (size_t)bh * SEQ * DH;
  const bf16* Vt = Vtg + (size_t)bh * DH * SEQ;
  int q0 = qt * 128 + qg * 16;

  // Q as B-operand: B[n=q(ln)][k=d(quad*8+j)] — Q already carries QSCALE
  bf16x8 bq[2];
#pragma unroll
  for (int kc = 0; kc < 2; ++kc)
    bq[kc] = *(const bf16x8*)&Q[(size_t)(q0 + ln) * DH + kc * 32 + quad * 8];

  // constant-ones B fragment for the l-accumulating MFMA
  bf16x8 ones;
#pragma unroll
  for (int j = 0; j < 8; ++j) ones[j] = (bf16)1.0f;

  floatx4 oacc[4];
  floatx4 oL = floatx4{0.f, 0.f, 0.f, 0.f};
#pragma unroll
  for (int dt = 0; dt < 4; ++dt) oacc[dt] = floatx4{0.f, 0.f, 0.f, 0.f};

  // staging roles: threads [0,512) stage half 0's tiles, [512,1024) half 1's.
  // Within a half: j<256 -> K (32B/thread), j>=256 -> V (32B/thread).
  int sh = t >> 9, st = t & 511;
  int ar = st >> 8, j = st & 255;
  int kr = j >> 2, kcol = (j & 3) * 16;  // row 0..63, 32B col chunk
  const bf16* gsrc;
  bf16* ldst;
  int gstep;
  if (ar == 0) {
    gsrc = K + (size_t)(sh * 1024 + kr) * DH + kcol;   // K row kr, d-chunk
    ldst = Ks + sh * 4608 + kr * 72 + kcol;
    gstep = 64 * DH;                                   // 64 keys per tile
  } else {
    gsrc = Vt + (size_t)kr * SEQ + sh * 1024 + kcol;   // V^T d=kr, key-chunk
    ldst = Vs + sh * 4608 + kr * 72 + kcol;
    gstep = 64;                                        // 64 keys per tile
  }

  bf16x8 p0 = *(const bf16x8*)gsrc;
  bf16x8 p1 = *(const bf16x8*)(gsrc + 8);

  const bf16* Ksh = Ks + half * 4608;
  const bf16* Vsh = Vs + half * 4608;
  bf16* Pw = Ps + w * (16 * 72);

  for (int it = 0; it < 16; ++it) {
    __syncthreads();
    *(bf16x8*)ldst = p0;
    *(bf16x8*)(ldst + 8) = p1;
    __syncthreads();

    if (it + 1 < 16) {
      const bf16* gnext = gsrc + (size_t)(it + 1) * gstep;
      p0 = *(const bf16x8*)gnext;
      p1 = *(const bf16x8*)(gnext + 8);
    }

    // S^T = K.Q^T: D[m=key][n=q]; s[nt][r] = score(q=ln, key=nt*16+quad*4+r)
    floatx4 s[4];
#pragma unroll
    for (int nt = 0; nt < 4; ++nt) s[nt] = floatx4{0.f, 0.f, 0.f, 0.f};
#pragma unroll
    for (int kc = 0; kc < 2; ++kc) {
#pragma unroll
      for (int nt = 0; nt < 4; ++nt) {
        bf16x8 ak = *(const bf16x8*)&Ksh[(nt * 16 + ln) * 72 + kc * 32 + quad * 8];
        s[nt] = __builtin_amdgcn_mfma_f32_16x16x32_bf16(ak, bq[kc], s[nt], 0, 0, 0);
      }
    }

    // p = exp2(s), raw v_exp_f32; packed b64 P writes; NO scalar li adds
#pragma unroll
    for (int nt = 0; nt < 4; ++nt) {
      float p0f = __builtin_amdgcn_exp2f(s[nt][0]);
      float p1f = __builtin_amdgcn_exp2f(s[nt][1]);
      float p2f = __builtin_amdgcn_exp2f(s[nt][2]);
      float p3f = __builtin_amdgcn_exp2f(s[nt][3]);
      bf16x4 pq = {(bf16)p0f, (bf16)p1f, (bf16)p2f, (bf16)p3f};
      *(bf16x4*)&Pw[ln * 72 + nt * 16 + quad * 4] = pq;
    }

    // O += P.V: A = P[q][key] (m=q), B = V^T[d][key] (n=d); same-wave LDS order
    // l += P.1: same A, B = ones (const reg) -> lane's oL[r] = l(quad*4+r)
#pragma unroll
    for (int kc2 = 0; kc2 < 2; ++kc2) {
      bf16x8 ap = *(const bf16x8*)&Pw[ln * 72 + kc2 * 32 + quad * 8];
      oL = __builtin_amdgcn_mfma_f32_16x16x32_bf16(ap, ones, oL, 0, 0, 0);
#pragma unroll
      for (int dt = 0; dt < 4; ++dt) {
        bf16x8 bv = *(const bf16x8*)&Vsh[(dt * 16 + ln) * 72 + kc2 * 32 + quad * 8];
        oacc[dt] = __builtin_amdgcn_mfma_f32_16x16x32_bf16(ap, bv, oacc[dt], 0, 0, 0);
      }
    }
  }

  // ---- split-K merge: O = O_half0 + O_half1, l = l0 + l1 (exact) ----
  __syncthreads();  // all compute (and last-tile LDS reads) done; reuse smem
  if (half) {
    if (ln == 0) {
#pragma unroll
      for (int r = 0; r < 4; ++r) Lm[qg * 16 + quad * 4 + r] = oL[r];
    }
#pragma unroll
    for (int r = 0; r < 4; ++r) {
      int q = qg * 16 + quad * 4 + r;
#pragma unroll
      for (int dt = 0; dt < 4; ++dt) Om[q * 68 + dt * 16 + ln] = oacc[dt][r];
    }
  }
  __syncthreads();
  if (!half) {
#pragma unroll
    for (int r = 0; r < 4; ++r) {
      int qq = qg * 16 + quad * 4 + r;
      float lt = oL[r] + Lm[qq];   // own half's l (all ln identical) + other
      float inv = 1.0f / lt;
      int ns = qt * 128 + qq;
#pragma unroll
      for (int dt = 0; dt < 4; ++dt) {
        int d = dt * 16 + ln;
        float val = (oacc[dt][r] + Om[qq * 68 + d]) * inv;
        Og[((size_t)(b * SEQ + ns)) * EMBED + h * DH + d] = val;
      }
    }
  }
}

// ---------------------------------------------------------------------------
// ws (38 MB): q [0,4M) k [4M,8M) vt [8M,12M) wqt..wvt [12M,15M) xb [15M,19M)
// ---------------------------------------------------------------------------
extern "C" void kernel_launch(void* const* d_in, const int* in_sizes, int n_in,
                              void* d_out, int out_size, void* d_ws, size_t ws_size,
                              hipStream_t stream) {
  const int XEL = 2 * 2048 * 1024;
  const float *x, *Wq, *Wk, *Wv;
  if (in_sizes[0] == XEL) {
    x = (const float*)d_in[0];
    Wq = (const float*)d_in[1];
    Wk = (const float*)d_in[2];
    Wv = (const float*)d_in[3];
  } else {
    Wk = (const float*)d_in[0];
    Wq = (const float*)d_in[1];
    Wv = (const float*)d_in[2];
    x = (const float*)d_in[3];
  }
  bf16* ws = (bf16*)d_ws;

  const size_t M1 = 1024 * 1024;
  bf16* q_ws = ws;
  bf16* k_ws = ws + 4 * M1;
  bf16* vt_ws = ws + 8 * M1;
  bf16* wqt = ws + 12 * M1;
  bf16* wkt = ws + 13 * M1;
  bf16* wvt = ws + 14 * M1;
  bf16* xb = ws + 15 * M1;

  prep<<<dim3(256, 4), 256, 0, stream>>>(x, Wq, Wk, Wv, xb, wqt, wkt, wvt);
  qkv3<<<dim3(768), 256, 0, stream>>>(xb, wqt, wkt, wvt, q_ws, k_ws, vt_ws);
  flash<<<dim3(16, 32), 1024, 0, stream>>>(q_ws, k_ws, vt_ws, (float*)d_out);
}